// Round 7
// baseline (205.024 us; speedup 1.0000x reference)
//
#include <hip/hip_runtime.h>
#include <hip/hip_bf16.h>

using u16 = unsigned short;
using u32 = unsigned int;
using short8 = __attribute__((ext_vector_type(8))) short;  // 8 bf16
using f32x4  = __attribute__((ext_vector_type(4))) float;
using u32x4  = __attribute__((ext_vector_type(4))) u32;
using u32x2  = __attribute__((ext_vector_type(2))) u32;

union V16 { u32x4 u; short8 s; };

__device__ __forceinline__ u16 f2b(float f) {
  u32 u = __float_as_uint(f);
  u32 r = (u + 0x7FFFu + ((u >> 16) & 1u)) >> 16;
  return (u16)r;
}
__device__ __forceinline__ u32 pk2(u16 a, u16 b) {
  return (u32)a | ((u32)b << 16);
}
// packed f32->bf16 pair (RNE), single VOP3 instr (no builtin on gfx950)
__device__ __forceinline__ u32 cvtpk(float lo, float hi) {
  u32 r;
  asm("v_cvt_pk_bf16_f32 %0, %1, %2" : "=v"(r) : "v"(lo), "v"(hi));
  return r;
}
// async global->LDS, 16B per lane; dest = wave-uniform base + lane*16 (linear)
__device__ __forceinline__ void gld16(const u16* g, u16* l) {
  __builtin_amdgcn_global_load_lds(
      (const __attribute__((address_space(1))) u32*)g,
      (__attribute__((address_space(3))) u32*)l, 16, 0, 0);
}

// ---------------------------------------------------------------------------
// Kernel 1: weight transpose + f32->bf16 convert.  out[n][k] = in[k][n]
// ---------------------------------------------------------------------------
__global__ __launch_bounds__(256) void wconv(
    const float* __restrict__ Wq, const float* __restrict__ Wk,
    const float* __restrict__ Wv, const float* __restrict__ Wo,
    u16* __restrict__ Wt, u16* __restrict__ WoT)
{
  __shared__ u16 t_[32][33];
  const int zz = blockIdx.z;
  const float* src = (zz == 0) ? Wq : (zz == 1) ? Wk : (zz == 2) ? Wv : Wo;
  u16* dst = (zz < 3) ? (Wt + (size_t)zz * 1048576) : WoT;
  const int n0 = blockIdx.x * 32, k0 = blockIdx.y * 32;
  const int tx = threadIdx.x, ty = threadIdx.y;
#pragma unroll
  for (int r = ty; r < 32; r += 8)
    t_[tx][r] = f2b(src[(size_t)(k0 + r) * 1024 + n0 + tx]);
  __syncthreads();
#pragma unroll
  for (int r = ty; r < 32; r += 8)
    dst[(size_t)(n0 + r) * 1024 + k0 + tx] = t_[r][tx];
}

// ---------------------------------------------------------------------------
// Kernel 1b: mask -> additive f32 bias (0 or -1e30), into dead Wt region.
// ---------------------------------------------------------------------------
__global__ __launch_bounds__(256) void mkbias(
    const int* __restrict__ mask, float* __restrict__ mb)
{
  const int i = blockIdx.x * 256 + threadIdx.x;  // 4096 total
  mb[i] = mask[i] ? 0.f : -1e30f;
}

// ---------------------------------------------------------------------------
// Kernel 2: QKV projection GEMM.  C = A(f32)[4096x1024] @ W[1024x1024]
// BK=64.  LDS holds A,B tiles in FRAGMENT-IMAGE order: 16 chunks x 64 lanes x
// 16B; chunk c=(o*8 + f*2 + kk): lane l <-> elem [o*64+f*16+(l&15)][kk*32+(l>>4)*8].
// B staged via global_load_lds (per-lane source, linear LDS dest); A reg-staged
// f32->bf16 via v_cvt_pk.  All ds_write/ds_read lane-linear -> zero conflicts.
// Epilogues: Q -> [b][h][n][64]; K,V -> attention fragment-image tiles.
// ---------------------------------------------------------------------------
__global__ __launch_bounds__(256) void gemm_qkv_k(
    const float* __restrict__ Aq, const float* __restrict__ Ak, const float* __restrict__ Av,
    const u16* __restrict__ Wt,
    u16* __restrict__ Qw, u16* __restrict__ Kw, u16* __restrict__ Vw)
{
  const int z = blockIdx.z;
  const float* A = (z == 0) ? Aq : (z == 1) ? Ak : Av;
  const u16* B = Wt + (size_t)z * 1048576;
  u16* O = (z == 0) ? Qw : (z == 1) ? Kw : Vw;

  __shared__ u16 As[16 * 512];  // A fragment image, 16KB
  __shared__ u16 Bs[16 * 512];  // B fragment image, 16KB

  const int tid = threadIdx.x;
  const int w = tid >> 6, l = tid & 63, lg = l >> 4, ll = l & 15;
  const int wr = w >> 1, wc = w & 1;
  const int m0 = blockIdx.y * 128, n0 = blockIdx.x * 128;

  f32x4 acc[4][4];
#pragma unroll
  for (int i = 0; i < 4; ++i)
#pragma unroll
    for (int t = 0; t < 4; ++t)
      acc[i][t] = (f32x4){0.f, 0.f, 0.f, 0.f};

  for (int ks = 0; ks < 16; ++ks) {
    __syncthreads();  // previous fragment reads done
    // B: 4 chunks per wave via global_load_lds (per-lane src, linear dest)
#pragma unroll
    for (int q = 0; q < 4; ++q) {
      const int c = q * 4 + w;
      const int row = n0 + (c >> 3) * 64 + ((c >> 1) & 3) * 16 + ll;
      const int col = ks * 64 + (c & 1) * 32 + lg * 8;
      gld16(B + (size_t)row * 1024 + col, &Bs[c * 512]);
    }
    // A: 4 chunk-slots per thread, reg-staged f32->bf16
#pragma unroll
    for (int q = 0; q < 4; ++q) {
      const int c = q * 4 + w;
      const int row = m0 + (c >> 3) * 64 + ((c >> 1) & 3) * 16 + ll;
      const int col = ks * 64 + (c & 1) * 32 + lg * 8;
      const f32x4* ap = (const f32x4*)(A + (size_t)row * 1024 + col);
      f32x4 x0 = ap[0], x1 = ap[1];
      u32x4 u;
      u[0] = cvtpk(x0[0], x0[1]); u[1] = cvtpk(x0[2], x0[3]);
      u[2] = cvtpk(x1[0], x1[1]); u[3] = cvtpk(x1[2], x1[3]);
      *(u32x4*)&As[c * 512 + l * 8] = u;
    }
    __syncthreads();  // staged tile visible (vmcnt+lgkm drained)

    short8 af[4], bf[4];
#pragma unroll
    for (int kk = 0; kk < 2; ++kk) {
#pragma unroll
      for (int i = 0; i < 4; ++i) {
        V16 v; v.u = *(const u32x4*)&As[(wr * 8 + i * 2 + kk) * 512 + l * 8];
        af[i] = v.s;
      }
#pragma unroll
      for (int t = 0; t < 4; ++t) {
        V16 v; v.u = *(const u32x4*)&Bs[(wc * 8 + t * 2 + kk) * 512 + l * 8];
        bf[t] = v.s;
      }
#pragma unroll
      for (int i = 0; i < 4; ++i)
#pragma unroll
        for (int t = 0; t < 4; ++t)
          acc[i][t] = __builtin_amdgcn_mfma_f32_16x16x32_bf16(af[i], bf[t], acc[i][t], 0, 0, 0);
    }
  }

  if (z == 0) {
    // Q: [b][h][n][64]
#pragma unroll
    for (int i = 0; i < 4; ++i)
#pragma unroll
      for (int te = 0; te < 4; ++te) {
        const int n = n0 + wc * 64 + te * 16 + ll;
        const int h = n >> 6, dd = n & 63;
#pragma unroll
        for (int j = 0; j < 4; ++j) {
          const int m = m0 + wr * 64 + i * 16 + lg * 4 + j;
          const int bb = m >> 11, pos = m & 2047;
          O[((size_t)(bb * 16 + h) * 2048 + pos) * 64 + dd] = f2b(acc[i][te][j]);
        }
      }
  } else if (z == 1) {
    // K fragment image: chunk t*2+s, lane lgk*16+ll2, elem e
#pragma unroll
    for (int i = 0; i < 4; ++i)
#pragma unroll
      for (int te = 0; te < 4; ++te) {
        const int n = n0 + wc * 64 + te * 16 + ll;
        const int h = n >> 6, dd = n & 63;
        const int s = dd >> 5, lgk = (dd >> 3) & 3, e = dd & 7;
#pragma unroll
        for (int j = 0; j < 4; ++j) {
          const int m = m0 + wr * 64 + i * 16 + lg * 4 + j;
          const int bb = m >> 11, pos = m & 2047;
          const int kt2 = pos >> 6, r = pos & 63;
          const int t2 = ((r >> 5) << 1) | ((r >> 2) & 1);
          const int ll2 = (((r >> 3) & 3) << 2) | (r & 3);
          O[((size_t)((bb * 16 + h) * 32 + kt2)) * 4096 + (t2 * 2 + s) * 512 + (lgk * 16 + ll2) * 8 + e]
              = f2b(acc[i][te][j]);
        }
      }
  } else {
    // V fragment image: chunk s*4+td, lane lgv*16+llv, elems e0..e0+3 (8B store)
#pragma unroll
    for (int i = 0; i < 4; ++i)
#pragma unroll
      for (int te = 0; te < 4; ++te) {
        const int n = n0 + wc * 64 + te * 16 + ll;
        const int h = n >> 6, dd = n & 63;
        const int td = dd >> 4, llv = dd & 15;
        const int mb0 = m0 + wr * 64 + i * 16 + lg * 4;   // j = 0
        const int bb = mb0 >> 11, pos = mb0 & 2047;
        const int kt2 = pos >> 6, kk = pos & 63;
        const int s = kk >> 5, lgv = (kk >> 3) & 3, e0 = kk & 7;
        u32x2 wv;
        wv[0] = pk2(f2b(acc[i][te][0]), f2b(acc[i][te][1]));
        wv[1] = pk2(f2b(acc[i][te][2]), f2b(acc[i][te][3]));
        *(u32x2*)&O[((size_t)((bb * 16 + h) * 32 + kt2)) * 4096 + (s * 4 + td) * 512 + (lgv * 16 + llv) * 8 + e0]
            = wv;
      }
  }
}

// ---------------------------------------------------------------------------
// Kernel 3: flash attention with fragment-image LDS staging (unchanged).
// ---------------------------------------------------------------------------
__global__ __launch_bounds__(256) void attn_k(
    const u16* __restrict__ Q, const u16* __restrict__ Kt, const u16* __restrict__ Vt,
    const float* __restrict__ mbias, u16* __restrict__ X)
{
  __shared__ u16 Ls[8192];  // [0,4096): K image tile; [4096,8192): V image tile

  const int tid = threadIdx.x;
  const int w = tid >> 6, l = tid & 63, lg = l >> 4, ll = l & 15;
  const int qb = blockIdx.x, h = blockIdx.y, b = blockIdx.z;
  const size_t qbase = (size_t)(b * 16 + h) * 2048 * 64;
  const size_t tbase = (size_t)((b * 16 + h) * 32) * 4096;
  const int q0 = qb * 64 + w * 16;

  short8 aq[2];
#pragma unroll
  for (int s = 0; s < 2; ++s) {
    V16 v; v.u = *(const u32x4*)&Q[qbase + (size_t)(q0 + ll) * 64 + s * 32 + lg * 8];
    aq[s] = v.s;
  }

  float mrow = -1e30f, lrow = 0.f;
  f32x4 o[4];
#pragma unroll
  for (int td = 0; td < 4; ++td) o[td] = (f32x4){0.f, 0.f, 0.f, 0.f};

  u32x4 rg[4];
#pragma unroll
  for (int q = 0; q < 4; ++q) {
    const int c = w * 4 + q;
    const u16* src = (c < 8) ? Kt : Vt;
    rg[q] = *(const u32x4*)&src[tbase + (c & 7) * 512 + l * 8];
  }

  for (int kt = 0; kt < 32; ++kt) {
    const int j0 = kt * 64;
    __syncthreads();

#pragma unroll
    for (int q = 0; q < 4; ++q) {
      const int c = w * 4 + q;
      *(u32x4*)&Ls[c * 512 + l * 8] = rg[q];
    }
    if (kt + 1 < 32) {
#pragma unroll
      for (int q = 0; q < 4; ++q) {
        const int c = w * 4 + q;
        const u16* src = (c < 8) ? Kt : Vt;
        rg[q] = *(const u32x4*)&src[tbase + (size_t)(kt + 1) * 4096 + (c & 7) * 512 + l * 8];
      }
    }
    __syncthreads();

    f32x4 sc[4];
#pragma unroll
    for (int t = 0; t < 4; ++t) {
      short8 bk0, bk1;
      { V16 v; v.u = *(const u32x4*)&Ls[(t * 2 + 0) * 512 + l * 8]; bk0 = v.s; }
      { V16 v; v.u = *(const u32x4*)&Ls[(t * 2 + 1) * 512 + l * 8]; bk1 = v.s; }
      f32x4 a = (f32x4){0.f, 0.f, 0.f, 0.f};
      a = __builtin_amdgcn_mfma_f32_16x16x32_bf16(bk0, aq[0], a, 0, 0, 0);
      a = __builtin_amdgcn_mfma_f32_16x16x32_bf16(bk1, aq[1], a, 0, 0, 0);
      const f32x4 mb = *(const f32x4*)&mbias[b * 2048 + j0 + ((t >> 1) << 5) + ((t & 1) << 2) + (lg << 3)];
#pragma unroll
      for (int j = 0; j < 4; ++j)
        sc[t][j] = a[j] * 0.125f + mb[j];
    }

    f32x4 mx4;
#pragma unroll
    for (int j = 0; j < 4; ++j)
      mx4[j] = fmaxf(fmaxf(sc[0][j], sc[1][j]), fmaxf(sc[2][j], sc[3][j]));
    float rm = fmaxf(fmaxf(mx4[0], mx4[1]), fmaxf(mx4[2], mx4[3]));
    rm = fmaxf(rm, __shfl_xor(rm, 16));
    rm = fmaxf(rm, __shfl_xor(rm, 32));

    const float mn = fmaxf(mrow, rm);
    const float alpha = __expf(mrow - mn);
    mrow = mn;

    f32x4 p4[4];
    f32x4 s4 = (f32x4){0.f, 0.f, 0.f, 0.f};
#pragma unroll
    for (int t = 0; t < 4; ++t) {
#pragma unroll
      for (int j = 0; j < 4; ++j) {
        p4[t][j] = __expf(sc[t][j] - mn);
        s4[j] += p4[t][j];
      }
    }
    float rs = (s4[0] + s4[1]) + (s4[2] + s4[3]);
    rs += __shfl_xor(rs, 16);
    rs += __shfl_xor(rs, 32);
    lrow = lrow * alpha + rs;
#pragma unroll
    for (int td = 0; td < 4; ++td)
#pragma unroll
      for (int j = 0; j < 4; ++j)
        o[td][j] *= alpha;

#pragma unroll
    for (int s = 0; s < 2; ++s) {
      V16 pb;
      pb.u[0] = cvtpk(p4[2 * s][0], p4[2 * s][1]);
      pb.u[1] = cvtpk(p4[2 * s][2], p4[2 * s][3]);
      pb.u[2] = cvtpk(p4[2 * s + 1][0], p4[2 * s + 1][1]);
      pb.u[3] = cvtpk(p4[2 * s + 1][2], p4[2 * s + 1][3]);
#pragma unroll
      for (int td = 0; td < 4; ++td) {
        V16 v; v.u = *(const u32x4*)&Ls[4096 + (s * 4 + td) * 512 + l * 8];
        o[td] = __builtin_amdgcn_mfma_f32_16x16x32_bf16(v.s, pb.s, o[td], 0, 0, 0);
      }
    }
  }

  const float inv = 1.f / lrow;
  u16* xp = &X[((size_t)(b * 2048 + q0 + ll)) * 1024 + h * 64 + lg * 4];
#pragma unroll
  for (int td = 0; td < 4; ++td) {
    u32x2 wv;
    wv[0] = cvtpk(o[td][0] * inv, o[td][1] * inv);
    wv[1] = cvtpk(o[td][2] * inv, o[td][3] * inv);
    *(u32x2*)&xp[td * 16] = wv;
  }
}

// ---------------------------------------------------------------------------
// Kernel 4: output GEMM + bias.  out = X(bf16)[4096x1024] @ Wo + bo, f32 out.
// Both operands staged via global_load_lds into fragment-image LDS.  BK=64.
// ---------------------------------------------------------------------------
__global__ __launch_bounds__(256) void gemm_out_k(
    const u16* __restrict__ Xw, const u16* __restrict__ WoT,
    const float* __restrict__ bo, float* __restrict__ out)
{
  __shared__ u16 As[16 * 512];
  __shared__ u16 Bs[16 * 512];

  const int tid = threadIdx.x;
  const int w = tid >> 6, l = tid & 63, lg = l >> 4, ll = l & 15;
  const int wr = w >> 1, wc = w & 1;
  const int m0 = blockIdx.y * 128, n0 = blockIdx.x * 128;

  f32x4 acc[4][4];
#pragma unroll
  for (int i = 0; i < 4; ++i)
#pragma unroll
    for (int t = 0; t < 4; ++t)
      acc[i][t] = (f32x4){0.f, 0.f, 0.f, 0.f};

  for (int ks = 0; ks < 16; ++ks) {
    __syncthreads();
#pragma unroll
    for (int q = 0; q < 4; ++q) {
      const int c = q * 4 + w;
      const int rowb = n0 + (c >> 3) * 64 + ((c >> 1) & 3) * 16 + ll;
      const int rowa = m0 + (c >> 3) * 64 + ((c >> 1) & 3) * 16 + ll;
      const int col = ks * 64 + (c & 1) * 32 + lg * 8;
      gld16(WoT + (size_t)rowb * 1024 + col, &Bs[c * 512]);
      gld16(Xw + (size_t)rowa * 1024 + col, &As[c * 512]);
    }
    __syncthreads();

    short8 af[4], bf[4];
#pragma unroll
    for (int kk = 0; kk < 2; ++kk) {
#pragma unroll
      for (int i = 0; i < 4; ++i) {
        V16 v; v.u = *(const u32x4*)&As[(wr * 8 + i * 2 + kk) * 512 + l * 8];
        af[i] = v.s;
      }
#pragma unroll
      for (int t = 0; t < 4; ++t) {
        V16 v; v.u = *(const u32x4*)&Bs[(wc * 8 + t * 2 + kk) * 512 + l * 8];
        bf[t] = v.s;
      }
#pragma unroll
      for (int i = 0; i < 4; ++i)
#pragma unroll
        for (int t = 0; t < 4; ++t)
          acc[i][t] = __builtin_amdgcn_mfma_f32_16x16x32_bf16(af[i], bf[t], acc[i][t], 0, 0, 0);
    }
  }

#pragma unroll
  for (int i = 0; i < 4; ++i)
#pragma unroll
    for (int t = 0; t < 4; ++t) {
      const int n = n0 + wc * 64 + t * 16 + ll;
      const float bv = bo[n];
#pragma unroll
      for (int j = 0; j < 4; ++j) {
        const int m = m0 + wr * 64 + i * 16 + lg * 4 + j;
        out[(size_t)m * 1024 + n] = acc[i][t][j] + bv;
      }
    }
}

// ---------------------------------------------------------------------------
extern "C" void kernel_launch(void* const* d_in, const int* in_sizes, int n_in,
                              void* d_out, int out_size, void* d_ws, size_t ws_size,
                              hipStream_t stream) {
  const float* qry = (const float*)d_in[0];
  const float* key = (const float*)d_in[1];
  const float* val = (const float*)d_in[2];
  const int* mask  = (const int*)d_in[3];
  const float* Wq  = (const float*)d_in[4];
  const float* Wk  = (const float*)d_in[5];
  const float* Wv  = (const float*)d_in[6];
  const float* Wo  = (const float*)d_in[7];
  const float* bo  = (const float*)d_in[8];
  float* out = (float*)d_out;

  char* ws = (char*)d_ws;
  u16* Wt  = (u16*)(ws);                 // 3 x 1024x1024 bf16 = 6 MB
  u16* WoT = (u16*)(ws + 6291456);       // 2 MB
  u16* Qw  = (u16*)(ws + 8388608);       // 8 MB  [b][h][n][64]
  u16* Kw  = (u16*)(ws + 16777216);      // 8 MB  K fragment-image tiles
  u16* Vw  = (u16*)(ws + 25165824);      // 8 MB  V fragment-image tiles
  u16* Xw  = (u16*)(ws + 33554432);      // 8 MB  [b*n][1024]
  float* mbias = (float*)(ws);           // 16 KB, reuses Wt region after gemm_qkv

  wconv<<<dim3(32, 32, 4), dim3(32, 8, 1), 0, stream>>>(Wq, Wk, Wv, Wo, Wt, WoT);
  gemm_qkv_k<<<dim3(8, 32, 3), 256, 0, stream>>>(qry, key, val, Wt, Qw, Kw, Vw);
  mkbias<<<dim3(16, 1, 1), 256, 0, stream>>>(mask, mbias);
  attn_k<<<dim3(32, 16, 2), 256, 0, stream>>>(Qw, Kw, Vw, mbias, Xw);
  gemm_out_k<<<dim3(8, 32, 1), 256, 0, stream>>>(Xw, WoT, bo, out);
}

// Round 8
// 196.183 us; speedup vs baseline: 1.0451x; 1.0451x over previous
//
#include <hip/hip_runtime.h>
#include <hip/hip_bf16.h>

using u16 = unsigned short;
using u32 = unsigned int;
using short8 = __attribute__((ext_vector_type(8))) short;  // 8 bf16
using f32x4  = __attribute__((ext_vector_type(4))) float;
using u32x4  = __attribute__((ext_vector_type(4))) u32;
using u32x2  = __attribute__((ext_vector_type(2))) u32;

union V16 { u32x4 u; short8 s; };

__device__ __forceinline__ u16 f2b(float f) {
  u32 u = __float_as_uint(f);
  u32 r = (u + 0x7FFFu + ((u >> 16) & 1u)) >> 16;
  return (u16)r;
}
__device__ __forceinline__ u32 pk2(u16 a, u16 b) {
  return (u32)a | ((u32)b << 16);
}
// packed f32->bf16 pair (RNE), single VOP3 instr (no builtin on gfx950)
__device__ __forceinline__ u32 cvtpk(float lo, float hi) {
  u32 r;
  asm("v_cvt_pk_bf16_f32 %0, %1, %2" : "=v"(r) : "v"(lo), "v"(hi));
  return r;
}
// async global->LDS, 16B per lane; dest = wave-uniform base + lane*16 (linear)
__device__ __forceinline__ void gld16(const u16* g, u16* l) {
  __builtin_amdgcn_global_load_lds(
      (const __attribute__((address_space(1))) u32*)g,
      (__attribute__((address_space(3))) u32*)l, 16, 0, 0);
}

// ---------------------------------------------------------------------------
// Kernel 1: weight -> bf16 FRAGMENT-IMAGE relayout.
// Image[z][nt][ks][c][l][e] = W[k][n],  k = ks*64 + (c&1)*32 + (l>>4)*8 + e,
//                                       n = nt*128 + (c>>3)*64 + ((c>>1)&3)*16 + (l&15)
// so GEMM B-staging is a contiguous lane-linear 1KB gld16 per chunk.
// ---------------------------------------------------------------------------
__global__ __launch_bounds__(256) void wconv(
    const float* __restrict__ Wq, const float* __restrict__ Wk,
    const float* __restrict__ Wv, const float* __restrict__ Wo,
    u16* __restrict__ Wt, u16* __restrict__ WoT)
{
  __shared__ u16 T[64][130];
  const int zz = blockIdx.z;
  const float* src = (zz == 0) ? Wq : (zz == 1) ? Wk : (zz == 2) ? Wv : Wo;
  u16* dst = (zz < 3) ? (Wt + (size_t)zz * 1048576) : WoT;
  const int nt = blockIdx.x, ks = blockIdx.y;
  const int tid = threadIdx.x;

  // load W[k = ks*64 + kl][n = nt*128 + nl], convert to bf16, into LDS
  {
    const int kl = tid >> 2, nl0 = (tid & 3) * 32;
    const float* sp = src + (size_t)(ks * 64 + kl) * 1024 + nt * 128 + nl0;
#pragma unroll
    for (int i = 0; i < 8; ++i) {
      f32x4 x = *(const f32x4*)(sp + i * 4);
      T[kl][nl0 + i * 4 + 0] = f2b(x[0]);
      T[kl][nl0 + i * 4 + 1] = f2b(x[1]);
      T[kl][nl0 + i * 4 + 2] = f2b(x[2]);
      T[kl][nl0 + i * 4 + 3] = f2b(x[3]);
    }
  }
  __syncthreads();

  // write fragment image: thread owns 4 lanes x 8 elems = 64B contiguous
  const int c = tid >> 4, l0 = (tid & 15) * 4;
  u16* dp = dst + ((size_t)(nt * 16 + ks) * 16 + c) * 512 + l0 * 8;
#pragma unroll
  for (int dl = 0; dl < 4; ++dl) {
    const int l = l0 + dl;
    const int kl = (c & 1) * 32 + (l >> 4) * 8;
    const int nl = (c >> 3) * 64 + ((c >> 1) & 3) * 16 + (l & 15);
    u32x4 u;
#pragma unroll
    for (int p = 0; p < 4; ++p)
      u[p] = pk2(T[kl + 2 * p][nl], T[kl + 2 * p + 1][nl]);
    *(u32x4*)(dp + dl * 8) = u;
  }
}

// ---------------------------------------------------------------------------
// Kernel 1b: mask -> additive f32 bias (0 or -1e30), into dead Wt region.
// ---------------------------------------------------------------------------
__global__ __launch_bounds__(256) void mkbias(
    const int* __restrict__ mask, float* __restrict__ mb)
{
  const int i = blockIdx.x * 256 + threadIdx.x;  // 4096 total
  mb[i] = mask[i] ? 0.f : -1e30f;
}

// ---------------------------------------------------------------------------
// Kernel 2: QKV projection GEMM.  C = A(f32)[4096x1024] @ W[1024x1024]
// BK=64, double-buffered fragment-image LDS, ONE barrier per K-step:
//   stage(k+1) issued (gld B contiguous, A f32->cvtpk regs) BEFORE tile-k
//   MFMAs; ds_write A late; single __syncthreads drains vmcnt under compute.
// Epilogues: Q -> [b][h][n][64]; K,V -> attention fragment-image tiles.
// ---------------------------------------------------------------------------
__global__ __launch_bounds__(256) void gemm_qkv_k(
    const float* __restrict__ Aq, const float* __restrict__ Ak, const float* __restrict__ Av,
    const u16* __restrict__ Wt,
    u16* __restrict__ Qw, u16* __restrict__ Kw, u16* __restrict__ Vw)
{
  const int z = blockIdx.z;
  const float* A = (z == 0) ? Aq : (z == 1) ? Ak : Av;
  const u16* Bf = Wt + (size_t)z * 1048576;
  u16* O = (z == 0) ? Qw : (z == 1) ? Kw : Vw;

  __shared__ u16 As[2][8192];
  __shared__ u16 Bs[2][8192];

  const int tid = threadIdx.x;
  const int w = tid >> 6, l = tid & 63, lg = l >> 4, ll = l & 15;
  const int wr = w >> 1, wc = w & 1;
  const int nt = blockIdx.x;
  const int m0 = blockIdx.y * 128, n0 = nt * 128;
  const size_t bbase = (size_t)nt * 16 * 8192;

  f32x4 acc[4][4];
#pragma unroll
  for (int i = 0; i < 4; ++i)
#pragma unroll
    for (int t = 0; t < 4; ++t)
      acc[i][t] = (f32x4){0.f, 0.f, 0.f, 0.f};

  f32x4 xa[4][2];

  // ---- prologue: stage ks=0 into buf 0
#pragma unroll
  for (int q = 0; q < 4; ++q) {
    const int c = q * 4 + w;
    gld16(Bf + bbase + (size_t)c * 512 + l * 8, &Bs[0][c * 512]);
  }
#pragma unroll
  for (int q = 0; q < 4; ++q) {
    const int c = q * 4 + w;
    const int row = m0 + (c >> 3) * 64 + ((c >> 1) & 3) * 16 + ll;
    const f32x4* ap = (const f32x4*)(A + (size_t)row * 1024 + (c & 1) * 32 + lg * 8);
    xa[q][0] = ap[0]; xa[q][1] = ap[1];
  }
#pragma unroll
  for (int q = 0; q < 4; ++q) {
    const int c = q * 4 + w;
    u32x4 u;
    u[0] = cvtpk(xa[q][0][0], xa[q][0][1]); u[1] = cvtpk(xa[q][0][2], xa[q][0][3]);
    u[2] = cvtpk(xa[q][1][0], xa[q][1][1]); u[3] = cvtpk(xa[q][1][2], xa[q][1][3]);
    *(u32x4*)&As[0][c * 512 + l * 8] = u;
  }
  __syncthreads();

  for (int ks = 0; ks < 16; ++ks) {
    const int cur = ks & 1;
    // ---- issue next tile's loads first (latency hides under MFMAs below)
    if (ks + 1 < 16) {
#pragma unroll
      for (int q = 0; q < 4; ++q) {
        const int c = q * 4 + w;
        gld16(Bf + bbase + ((size_t)(ks + 1) * 16 + c) * 512 + l * 8, &Bs[cur ^ 1][c * 512]);
      }
#pragma unroll
      for (int q = 0; q < 4; ++q) {
        const int c = q * 4 + w;
        const int row = m0 + (c >> 3) * 64 + ((c >> 1) & 3) * 16 + ll;
        const f32x4* ap = (const f32x4*)(A + (size_t)row * 1024 + (ks + 1) * 64 + (c & 1) * 32 + lg * 8);
        xa[q][0] = ap[0]; xa[q][1] = ap[1];
      }
    }
    // ---- compute tile ks from buf cur
#pragma unroll
    for (int kk = 0; kk < 2; ++kk) {
      short8 af[4], bf[4];
#pragma unroll
      for (int i = 0; i < 4; ++i) {
        V16 v; v.u = *(const u32x4*)&As[cur][(wr * 8 + i * 2 + kk) * 512 + l * 8];
        af[i] = v.s;
      }
#pragma unroll
      for (int t = 0; t < 4; ++t) {
        V16 v; v.u = *(const u32x4*)&Bs[cur][(wc * 8 + t * 2 + kk) * 512 + l * 8];
        bf[t] = v.s;
      }
#pragma unroll
      for (int i = 0; i < 4; ++i)
#pragma unroll
        for (int t = 0; t < 4; ++t)
          acc[i][t] = __builtin_amdgcn_mfma_f32_16x16x32_bf16(af[i], bf[t], acc[i][t], 0, 0, 0);
    }
    // ---- write staged A into the other buffer (waits on A loads here, late)
    if (ks + 1 < 16) {
#pragma unroll
      for (int q = 0; q < 4; ++q) {
        const int c = q * 4 + w;
        u32x4 u;
        u[0] = cvtpk(xa[q][0][0], xa[q][0][1]); u[1] = cvtpk(xa[q][0][2], xa[q][0][3]);
        u[2] = cvtpk(xa[q][1][0], xa[q][1][1]); u[3] = cvtpk(xa[q][1][2], xa[q][1][3]);
        *(u32x4*)&As[cur ^ 1][c * 512 + l * 8] = u;
      }
    }
    __syncthreads();  // drains gld (vmcnt) + ds_writes once per K-step
  }

  if (z == 0) {
    // Q: [b][h][n][64]
#pragma unroll
    for (int i = 0; i < 4; ++i)
#pragma unroll
      for (int te = 0; te < 4; ++te) {
        const int n = n0 + wc * 64 + te * 16 + ll;
        const int h = n >> 6, dd = n & 63;
#pragma unroll
        for (int j = 0; j < 4; ++j) {
          const int m = m0 + wr * 64 + i * 16 + lg * 4 + j;
          const int bb = m >> 11, pos = m & 2047;
          O[((size_t)(bb * 16 + h) * 2048 + pos) * 64 + dd] = f2b(acc[i][te][j]);
        }
      }
  } else if (z == 1) {
    // K fragment image: chunk t*2+s, lane lgk*16+ll2, elem e
#pragma unroll
    for (int i = 0; i < 4; ++i)
#pragma unroll
      for (int te = 0; te < 4; ++te) {
        const int n = n0 + wc * 64 + te * 16 + ll;
        const int h = n >> 6, dd = n & 63;
        const int s = dd >> 5, lgk = (dd >> 3) & 3, e = dd & 7;
#pragma unroll
        for (int j = 0; j < 4; ++j) {
          const int m = m0 + wr * 64 + i * 16 + lg * 4 + j;
          const int bb = m >> 11, pos = m & 2047;
          const int kt2 = pos >> 6, r = pos & 63;
          const int t2 = ((r >> 5) << 1) | ((r >> 2) & 1);
          const int ll2 = (((r >> 3) & 3) << 2) | (r & 3);
          O[((size_t)((bb * 16 + h) * 32 + kt2)) * 4096 + (t2 * 2 + s) * 512 + (lgk * 16 + ll2) * 8 + e]
              = f2b(acc[i][te][j]);
        }
      }
  } else {
    // V fragment image: chunk s*4+td, lane lgv*16+llv, elems e0..e0+3 (8B store)
#pragma unroll
    for (int i = 0; i < 4; ++i)
#pragma unroll
      for (int te = 0; te < 4; ++te) {
        const int n = n0 + wc * 64 + te * 16 + ll;
        const int h = n >> 6, dd = n & 63;
        const int td = dd >> 4, llv = dd & 15;
        const int mb0 = m0 + wr * 64 + i * 16 + lg * 4;   // j = 0
        const int bb = mb0 >> 11, pos = mb0 & 2047;
        const int kt2 = pos >> 6, kk = pos & 63;
        const int s = kk >> 5, lgv = (kk >> 3) & 3, e0 = kk & 7;
        u32x2 wv;
        wv[0] = pk2(f2b(acc[i][te][0]), f2b(acc[i][te][1]));
        wv[1] = pk2(f2b(acc[i][te][2]), f2b(acc[i][te][3]));
        *(u32x2*)&O[((size_t)((bb * 16 + h) * 32 + kt2)) * 4096 + (s * 4 + td) * 512 + (lgv * 16 + llv) * 8 + e0]
            = wv;
      }
  }
}

// ---------------------------------------------------------------------------
// Kernel 3: flash attention (compute unchanged, verified).  Output now written
// in gemm_out's A fragment-image order:
//   Xf[((mt*16 + h)*16 + c)*512 + l*8 + e],
//   c = (mr>>6)*8 + ((mr>>4)&3)*2 + (td>>1), l = ((2*td+(lg>>1))&3)*16 + (mr&15),
//   e0 = (lg&1)*4, with m = b*2048+q0+ll, mt = m>>7, mr = m&127.
// ---------------------------------------------------------------------------
__global__ __launch_bounds__(256) void attn_k(
    const u16* __restrict__ Q, const u16* __restrict__ Kt, const u16* __restrict__ Vt,
    const float* __restrict__ mbias, u16* __restrict__ Xf)
{
  __shared__ u16 Ls[8192];  // [0,4096): K image tile; [4096,8192): V image tile

  const int tid = threadIdx.x;
  const int w = tid >> 6, l = tid & 63, lg = l >> 4, ll = l & 15;
  const int qb = blockIdx.x, h = blockIdx.y, b = blockIdx.z;
  const size_t qbase = (size_t)(b * 16 + h) * 2048 * 64;
  const size_t tbase = (size_t)((b * 16 + h) * 32) * 4096;
  const int q0 = qb * 64 + w * 16;

  short8 aq[2];
#pragma unroll
  for (int s = 0; s < 2; ++s) {
    V16 v; v.u = *(const u32x4*)&Q[qbase + (size_t)(q0 + ll) * 64 + s * 32 + lg * 8];
    aq[s] = v.s;
  }

  float mrow = -1e30f, lrow = 0.f;
  f32x4 o[4];
#pragma unroll
  for (int td = 0; td < 4; ++td) o[td] = (f32x4){0.f, 0.f, 0.f, 0.f};

  u32x4 rg[4];
#pragma unroll
  for (int q = 0; q < 4; ++q) {
    const int c = w * 4 + q;
    const u16* src = (c < 8) ? Kt : Vt;
    rg[q] = *(const u32x4*)&src[tbase + (c & 7) * 512 + l * 8];
  }

  for (int kt = 0; kt < 32; ++kt) {
    const int j0 = kt * 64;
    __syncthreads();

#pragma unroll
    for (int q = 0; q < 4; ++q) {
      const int c = w * 4 + q;
      *(u32x4*)&Ls[c * 512 + l * 8] = rg[q];
    }
    if (kt + 1 < 32) {
#pragma unroll
      for (int q = 0; q < 4; ++q) {
        const int c = w * 4 + q;
        const u16* src = (c < 8) ? Kt : Vt;
        rg[q] = *(const u32x4*)&src[tbase + (size_t)(kt + 1) * 4096 + (c & 7) * 512 + l * 8];
      }
    }
    __syncthreads();

    f32x4 sc[4];
#pragma unroll
    for (int t = 0; t < 4; ++t) {
      short8 bk0, bk1;
      { V16 v; v.u = *(const u32x4*)&Ls[(t * 2 + 0) * 512 + l * 8]; bk0 = v.s; }
      { V16 v; v.u = *(const u32x4*)&Ls[(t * 2 + 1) * 512 + l * 8]; bk1 = v.s; }
      f32x4 a = (f32x4){0.f, 0.f, 0.f, 0.f};
      a = __builtin_amdgcn_mfma_f32_16x16x32_bf16(bk0, aq[0], a, 0, 0, 0);
      a = __builtin_amdgcn_mfma_f32_16x16x32_bf16(bk1, aq[1], a, 0, 0, 0);
      const f32x4 mb = *(const f32x4*)&mbias[b * 2048 + j0 + ((t >> 1) << 5) + ((t & 1) << 2) + (lg << 3)];
#pragma unroll
      for (int j = 0; j < 4; ++j)
        sc[t][j] = a[j] * 0.125f + mb[j];
    }

    f32x4 mx4;
#pragma unroll
    for (int j = 0; j < 4; ++j)
      mx4[j] = fmaxf(fmaxf(sc[0][j], sc[1][j]), fmaxf(sc[2][j], sc[3][j]));
    float rm = fmaxf(fmaxf(mx4[0], mx4[1]), fmaxf(mx4[2], mx4[3]));
    rm = fmaxf(rm, __shfl_xor(rm, 16));
    rm = fmaxf(rm, __shfl_xor(rm, 32));

    const float mn = fmaxf(mrow, rm);
    const float alpha = __expf(mrow - mn);
    mrow = mn;

    f32x4 p4[4];
    f32x4 s4 = (f32x4){0.f, 0.f, 0.f, 0.f};
#pragma unroll
    for (int t = 0; t < 4; ++t) {
#pragma unroll
      for (int j = 0; j < 4; ++j) {
        p4[t][j] = __expf(sc[t][j] - mn);
        s4[j] += p4[t][j];
      }
    }
    float rs = (s4[0] + s4[1]) + (s4[2] + s4[3]);
    rs += __shfl_xor(rs, 16);
    rs += __shfl_xor(rs, 32);
    lrow = lrow * alpha + rs;
#pragma unroll
    for (int td = 0; td < 4; ++td)
#pragma unroll
      for (int j = 0; j < 4; ++j)
        o[td][j] *= alpha;

#pragma unroll
    for (int s = 0; s < 2; ++s) {
      V16 pb;
      pb.u[0] = cvtpk(p4[2 * s][0], p4[2 * s][1]);
      pb.u[1] = cvtpk(p4[2 * s][2], p4[2 * s][3]);
      pb.u[2] = cvtpk(p4[2 * s + 1][0], p4[2 * s + 1][1]);
      pb.u[3] = cvtpk(p4[2 * s + 1][2], p4[2 * s + 1][3]);
#pragma unroll
      for (int td = 0; td < 4; ++td) {
        V16 v; v.u = *(const u32x4*)&Ls[4096 + (s * 4 + td) * 512 + l * 8];
        o[td] = __builtin_amdgcn_mfma_f32_16x16x32_bf16(v.s, pb.s, o[td], 0, 0, 0);
      }
    }
  }

  // write X in gemm_out A fragment-image order (8B per td)
  const float inv = 1.f / lrow;
  const int m = b * 2048 + q0 + ll;
  const int mt = m >> 7, mr = m & 127;
  const int e0 = (lg & 1) * 4;
#pragma unroll
  for (int td = 0; td < 4; ++td) {
    const int c = ((mr >> 6) << 3) | (((mr >> 4) & 3) << 1) | (td >> 1);
    const int lA = (((td << 1) + (lg >> 1)) & 3) * 16 + (mr & 15);
    u32x2 wv;
    wv[0] = cvtpk(o[td][0] * inv, o[td][1] * inv);
    wv[1] = cvtpk(o[td][2] * inv, o[td][3] * inv);
    *(u32x2*)&Xf[((size_t)(mt * 16 + h) * 16 + c) * 512 + lA * 8 + e0] = wv;
  }
}

// ---------------------------------------------------------------------------
// Kernel 4: output GEMM + bias.  out = X(bf16)[4096x1024] @ Wo + bo, f32 out.
// Both operands contiguous fragment-image gld16, double-buffered, 1 barrier.
// ---------------------------------------------------------------------------
__global__ __launch_bounds__(256) void gemm_out_k(
    const u16* __restrict__ Xf, const u16* __restrict__ WoF,
    const float* __restrict__ bo, float* __restrict__ out)
{
  __shared__ u16 As[2][8192];
  __shared__ u16 Bs[2][8192];

  const int tid = threadIdx.x;
  const int w = tid >> 6, l = tid & 63, lg = l >> 4, ll = l & 15;
  const int wr = w >> 1, wc = w & 1;
  const int nt = blockIdx.x, mt = blockIdx.y;
  const int m0 = mt * 128, n0 = nt * 128;
  const size_t abase = (size_t)mt * 16 * 8192;
  const size_t bbase = (size_t)nt * 16 * 8192;

  f32x4 acc[4][4];
#pragma unroll
  for (int i = 0; i < 4; ++i)
#pragma unroll
    for (int t = 0; t < 4; ++t)
      acc[i][t] = (f32x4){0.f, 0.f, 0.f, 0.f};

#pragma unroll
  for (int q = 0; q < 4; ++q) {
    const int c = q * 4 + w;
    gld16(WoF + bbase + (size_t)c * 512 + l * 8, &Bs[0][c * 512]);
    gld16(Xf + abase + (size_t)c * 512 + l * 8, &As[0][c * 512]);
  }
  __syncthreads();

  for (int ks = 0; ks < 16; ++ks) {
    const int cur = ks & 1;
    if (ks + 1 < 16) {
#pragma unroll
      for (int q = 0; q < 4; ++q) {
        const int c = q * 4 + w;
        gld16(WoF + bbase + ((size_t)(ks + 1) * 16 + c) * 512 + l * 8, &Bs[cur ^ 1][c * 512]);
        gld16(Xf + abase + ((size_t)(ks + 1) * 16 + c) * 512 + l * 8, &As[cur ^ 1][c * 512]);
      }
    }
#pragma unroll
    for (int kk = 0; kk < 2; ++kk) {
      short8 af[4], bf[4];
#pragma unroll
      for (int i = 0; i < 4; ++i) {
        V16 v; v.u = *(const u32x4*)&As[cur][(wr * 8 + i * 2 + kk) * 512 + l * 8];
        af[i] = v.s;
      }
#pragma unroll
      for (int t = 0; t < 4; ++t) {
        V16 v; v.u = *(const u32x4*)&Bs[cur][(wc * 8 + t * 2 + kk) * 512 + l * 8];
        bf[t] = v.s;
      }
#pragma unroll
      for (int i = 0; i < 4; ++i)
#pragma unroll
        for (int t = 0; t < 4; ++t)
          acc[i][t] = __builtin_amdgcn_mfma_f32_16x16x32_bf16(af[i], bf[t], acc[i][t], 0, 0, 0);
    }
    __syncthreads();
  }

#pragma unroll
  for (int i = 0; i < 4; ++i)
#pragma unroll
    for (int t = 0; t < 4; ++t) {
      const int n = n0 + wc * 64 + t * 16 + ll;
      const float bv = bo[n];
#pragma unroll
      for (int j = 0; j < 4; ++j) {
        const int m = m0 + wr * 64 + i * 16 + lg * 4 + j;
        out[(size_t)m * 1024 + n] = acc[i][t][j] + bv;
      }
    }
}

// ---------------------------------------------------------------------------
extern "C" void kernel_launch(void* const* d_in, const int* in_sizes, int n_in,
                              void* d_out, int out_size, void* d_ws, size_t ws_size,
                              hipStream_t stream) {
  const float* qry = (const float*)d_in[0];
  const float* key = (const float*)d_in[1];
  const float* val = (const float*)d_in[2];
  const int* mask  = (const int*)d_in[3];
  const float* Wq  = (const float*)d_in[4];
  const float* Wk  = (const float*)d_in[5];
  const float* Wv  = (const float*)d_in[6];
  const float* Wo  = (const float*)d_in[7];
  const float* bo  = (const float*)d_in[8];
  float* out = (float*)d_out;

  char* ws = (char*)d_ws;
  u16* Wt  = (u16*)(ws);                 // 3 x 1M u16 fragment images = 6 MB
  u16* WoT = (u16*)(ws + 6291456);       // 2 MB fragment image
  u16* Qw  = (u16*)(ws + 8388608);       // 8 MB  [b][h][n][64]
  u16* Kw  = (u16*)(ws + 16777216);      // 8 MB  K attn fragment-image tiles
  u16* Vw  = (u16*)(ws + 25165824);      // 8 MB  V attn fragment-image tiles
  u16* Xw  = (u16*)(ws + 33554432);      // 8 MB  X gemm_out-A fragment image
  float* mbias = (float*)(ws);           // 16 KB, reuses Wt region after gemm_qkv

  wconv<<<dim3(8, 16, 4), 256, 0, stream>>>(Wq, Wk, Wv, Wo, Wt, WoT);
  gemm_qkv_k<<<dim3(8, 32, 3), 256, 0, stream>>>(qry, key, val, Wt, Qw, Kw, Vw);
  mkbias<<<dim3(16, 1, 1), 256, 0, stream>>>(mask, mbias);
  attn_k<<<dim3(32, 16, 2), 256, 0, stream>>>(Qw, Kw, Vw, mbias, Xw);
  gemm_out_k<<<dim3(8, 32, 1), 256, 0, stream>>>(Xw, WoT, bo, out);
}

// Round 9
// 158.236 us; speedup vs baseline: 1.2957x; 1.2398x over previous
//
#include <hip/hip_runtime.h>
#include <hip/hip_bf16.h>

using u16 = unsigned short;
using u32 = unsigned int;
using short8 = __attribute__((ext_vector_type(8))) short;  // 8 bf16
using f32x4  = __attribute__((ext_vector_type(4))) float;
using u32x4  = __attribute__((ext_vector_type(4))) u32;
using u32x2  = __attribute__((ext_vector_type(2))) u32;

union V16 { u32x4 u; short8 s; };

__device__ __forceinline__ u16 f2b(float f) {
  u32 u = __float_as_uint(f);
  u32 r = (u + 0x7FFFu + ((u >> 16) & 1u)) >> 16;
  return (u16)r;
}
__device__ __forceinline__ u32 pk2(u16 a, u16 b) {
  return (u32)a | ((u32)b << 16);
}
// packed f32->bf16 pair (RNE), single VOP3 instr (no builtin on gfx950)
__device__ __forceinline__ u32 cvtpk(float lo, float hi) {
  u32 r;
  asm("v_cvt_pk_bf16_f32 %0, %1, %2" : "=v"(r) : "v"(lo), "v"(hi));
  return r;
}
// async global->LDS, 16B per lane; dest = wave-uniform base + lane*16 (linear)
__device__ __forceinline__ void gld16(const u16* g, u16* l) {
  __builtin_amdgcn_global_load_lds(
      (const __attribute__((address_space(1))) u32*)g,
      (__attribute__((address_space(3))) u32*)l, 16, 0, 0);
}

// Fragment-image layout (shared by all GEMM operands):
//   img[(tile128*16 + ks)*16 + c][l][e],  c=chunk 0..15, l=lane 0..63, e=0..7
//   row(tile-local) = (c>>3)*64 + ((c>>1)&3)*16 + (l&15)
//   col(k)          = ks*64 + (c&1)*32 + (l>>4)*8 + e

// ---------------------------------------------------------------------------
// Kernel 1: weight -> bf16 fragment image (B operand).
// ---------------------------------------------------------------------------
__global__ __launch_bounds__(256) void wconv(
    const float* __restrict__ Wq, const float* __restrict__ Wk,
    const float* __restrict__ Wv, const float* __restrict__ Wo,
    u16* __restrict__ Wt, u16* __restrict__ WoT)
{
  __shared__ u16 T[64][130];
  const int zz = blockIdx.z;
  const float* src = (zz == 0) ? Wq : (zz == 1) ? Wk : (zz == 2) ? Wv : Wo;
  u16* dst = (zz < 3) ? (Wt + (size_t)zz * 1048576) : WoT;
  const int nt = blockIdx.x, ks = blockIdx.y;
  const int tid = threadIdx.x;

  {
    const int kl = tid >> 2, nl0 = (tid & 3) * 32;
    const float* sp = src + (size_t)(ks * 64 + kl) * 1024 + nt * 128 + nl0;
#pragma unroll
    for (int i = 0; i < 8; ++i) {
      f32x4 x = *(const f32x4*)(sp + i * 4);
      T[kl][nl0 + i * 4 + 0] = f2b(x[0]);
      T[kl][nl0 + i * 4 + 1] = f2b(x[1]);
      T[kl][nl0 + i * 4 + 2] = f2b(x[2]);
      T[kl][nl0 + i * 4 + 3] = f2b(x[3]);
    }
  }
  __syncthreads();

  const int c = tid >> 4, l0 = (tid & 15) * 4;
  u16* dp = dst + ((size_t)(nt * 16 + ks) * 16 + c) * 512 + l0 * 8;
#pragma unroll
  for (int dl = 0; dl < 4; ++dl) {
    const int l = l0 + dl;
    const int kl = (c & 1) * 32 + (l >> 4) * 8;
    const int nl = (c >> 3) * 64 + ((c >> 1) & 3) * 16 + (l & 15);
    u32x4 u;
#pragma unroll
    for (int p = 0; p < 4; ++p)
      u[p] = pk2(T[kl + 2 * p][nl], T[kl + 2 * p + 1][nl]);
    *(u32x4*)(dp + dl * 8) = u;
  }
}

// ---------------------------------------------------------------------------
// Kernel 1c: activation f32 -> bf16 fragment image (A operand).
// grid (16 ks, 32 mt, nz); z = blockIdx.z + z0; dst = Af + blockIdx.z*zstride.
// ---------------------------------------------------------------------------
__global__ __launch_bounds__(256) void aconv(
    const float* __restrict__ Aq, const float* __restrict__ Ak,
    const float* __restrict__ Av, u16* __restrict__ Af,
    int z0, size_t zstride)
{
  const int z = blockIdx.z + z0;
  const float* A = (z == 0) ? Aq : (z == 1) ? Ak : Av;
  u16* dst = Af + (size_t)blockIdx.z * zstride;
  const int ks = blockIdx.x, mt = blockIdx.y;
  const int tid = threadIdx.x;
  const int c = tid >> 4, l0 = (tid & 15) * 4;
  u16* dp = dst + ((size_t)(mt * 16 + ks) * 16 + c) * 512 + l0 * 8;
#pragma unroll
  for (int dl = 0; dl < 4; ++dl) {
    const int l = l0 + dl;
    const int rm = mt * 128 + (c >> 3) * 64 + ((c >> 1) & 3) * 16 + (l & 15);
    const int ck = ks * 64 + (c & 1) * 32 + (l >> 4) * 8;
    const f32x4* sp = (const f32x4*)(A + (size_t)rm * 1024 + ck);
    f32x4 x0 = sp[0], x1 = sp[1];
    u32x4 u;
    u[0] = cvtpk(x0[0], x0[1]); u[1] = cvtpk(x0[2], x0[3]);
    u[2] = cvtpk(x1[0], x1[1]); u[3] = cvtpk(x1[2], x1[3]);
    *(u32x4*)(dp + dl * 8) = u;
  }
}

// ---------------------------------------------------------------------------
// Kernel 1b: mask -> additive f32 bias (0 or -1e30), into dead Wt region.
// ---------------------------------------------------------------------------
__global__ __launch_bounds__(256) void mkbias(
    const int* __restrict__ mask, float* __restrict__ mb)
{
  const int i = blockIdx.x * 256 + threadIdx.x;  // 4096 total
  mb[i] = mask[i] ? 0.f : -1e30f;
}

// ---------------------------------------------------------------------------
// Kernel 2: QKV projection GEMM, pure fragment-image form.
// 512 thr = 8 waves (wave: 64 rows x 32 cols); 32KB LDS single-buffered;
// per K-step: ds_read 12 frags -> regs; barrier; issue 4 gld16 (next tile,
// same buffer); 16 MFMA from regs; barrier (drain hidden under MFMAs).
// ---------------------------------------------------------------------------
__global__ __launch_bounds__(512, 4) void gemm_qkv_k(
    const u16* __restrict__ Af, const u16* __restrict__ Wt,
    u16* __restrict__ Qw, u16* __restrict__ Kw, u16* __restrict__ Vw,
    int z0, size_t azs)
{
  __shared__ u16 As[8192];
  __shared__ u16 Bs[8192];

  const int z = blockIdx.z + z0;
  const u16* Aimg = Af + (size_t)blockIdx.z * azs;
  const u16* Bimg = Wt + (size_t)z * 1048576;
  u16* O = (z == 0) ? Qw : (z == 1) ? Kw : Vw;

  const int tid = threadIdx.x;
  const int w = tid >> 6, l = tid & 63, lg = l >> 4, ll = l & 15;
  const int wr = w >> 2, wc = w & 3;
  const int nt = blockIdx.x, mt = blockIdx.y;
  const size_t ab = (size_t)mt * 131072;
  const size_t bb = (size_t)nt * 131072;

  f32x4 acc[4][2];
#pragma unroll
  for (int i = 0; i < 4; ++i)
#pragma unroll
    for (int t = 0; t < 2; ++t)
      acc[i][t] = (f32x4){0.f, 0.f, 0.f, 0.f};

  // prologue: stage ks=0 (4 chunks per wave)
  gld16(Aimg + ab + (size_t)w * 512 + l * 8,       &As[w * 512]);
  gld16(Aimg + ab + (size_t)(w + 8) * 512 + l * 8, &As[(w + 8) * 512]);
  gld16(Bimg + bb + (size_t)w * 512 + l * 8,       &Bs[w * 512]);
  gld16(Bimg + bb + (size_t)(w + 8) * 512 + l * 8, &Bs[(w + 8) * 512]);
  __syncthreads();

  for (int ks = 0; ks < 16; ++ks) {
    short8 afr[2][4], bfr[2][2];
#pragma unroll
    for (int kk = 0; kk < 2; ++kk) {
#pragma unroll
      for (int i = 0; i < 4; ++i) {
        V16 v; v.u = *(const u32x4*)&As[(wr * 8 + i * 2 + kk) * 512 + l * 8];
        afr[kk][i] = v.s;
      }
#pragma unroll
      for (int t = 0; t < 2; ++t) {
        V16 v; v.u = *(const u32x4*)&Bs[((wc >> 1) * 8 + ((wc & 1) * 2 + t) * 2 + kk) * 512 + l * 8];
        bfr[kk][t] = v.s;
      }
    }
    __syncthreads();   // all waves done reading buf
    if (ks + 1 < 16) {
      const size_t ao = ab + (size_t)(ks + 1) * 8192;
      const size_t bo2 = bb + (size_t)(ks + 1) * 8192;
      gld16(Aimg + ao + (size_t)w * 512 + l * 8,       &As[w * 512]);
      gld16(Aimg + ao + (size_t)(w + 8) * 512 + l * 8, &As[(w + 8) * 512]);
      gld16(Bimg + bo2 + (size_t)w * 512 + l * 8,       &Bs[w * 512]);
      gld16(Bimg + bo2 + (size_t)(w + 8) * 512 + l * 8, &Bs[(w + 8) * 512]);
    }
#pragma unroll
    for (int kk = 0; kk < 2; ++kk)
#pragma unroll
      for (int i = 0; i < 4; ++i)
#pragma unroll
        for (int t = 0; t < 2; ++t)
          acc[i][t] = __builtin_amdgcn_mfma_f32_16x16x32_bf16(afr[kk][i], bfr[kk][t], acc[i][t], 0, 0, 0);
    __syncthreads();   // drain vmcnt: next tile resident
  }

  const int m0 = mt * 128, n0 = nt * 128;
  if (z == 0) {
#pragma unroll
    for (int i = 0; i < 4; ++i)
#pragma unroll
      for (int t = 0; t < 2; ++t) {
        const int n = n0 + wc * 32 + t * 16 + ll;
        const int h = n >> 6, dd = n & 63;
#pragma unroll
        for (int j = 0; j < 4; ++j) {
          const int m = m0 + wr * 64 + i * 16 + lg * 4 + j;
          const int bbk = m >> 11, pos = m & 2047;
          O[((size_t)(bbk * 16 + h) * 2048 + pos) * 64 + dd] = f2b(acc[i][t][j]);
        }
      }
  } else if (z == 1) {
#pragma unroll
    for (int i = 0; i < 4; ++i)
#pragma unroll
      for (int t = 0; t < 2; ++t) {
        const int n = n0 + wc * 32 + t * 16 + ll;
        const int h = n >> 6, dd = n & 63;
        const int s = dd >> 5, lgk = (dd >> 3) & 3, e = dd & 7;
#pragma unroll
        for (int j = 0; j < 4; ++j) {
          const int m = m0 + wr * 64 + i * 16 + lg * 4 + j;
          const int bbk = m >> 11, pos = m & 2047;
          const int kt2 = pos >> 6, r = pos & 63;
          const int t2 = ((r >> 5) << 1) | ((r >> 2) & 1);
          const int ll2 = (((r >> 3) & 3) << 2) | (r & 3);
          O[((size_t)((bbk * 16 + h) * 32 + kt2)) * 4096 + (t2 * 2 + s) * 512 + (lgk * 16 + ll2) * 8 + e]
              = f2b(acc[i][t][j]);
        }
      }
  } else {
#pragma unroll
    for (int i = 0; i < 4; ++i)
#pragma unroll
      for (int t = 0; t < 2; ++t) {
        const int n = n0 + wc * 32 + t * 16 + ll;
        const int h = n >> 6, dd = n & 63;
        const int td = dd >> 4, llv = dd & 15;
        const int mb0 = m0 + wr * 64 + i * 16 + lg * 4;   // j = 0
        const int bbk = mb0 >> 11, pos = mb0 & 2047;
        const int kt2 = pos >> 6, kk = pos & 63;
        const int s = kk >> 5, lgv = (kk >> 3) & 3, e0 = kk & 7;
        u32x2 wv;
        wv[0] = pk2(f2b(acc[i][t][0]), f2b(acc[i][t][1]));
        wv[1] = pk2(f2b(acc[i][t][2]), f2b(acc[i][t][3]));
        *(u32x2*)&O[((size_t)((bbk * 16 + h) * 32 + kt2)) * 4096 + (s * 4 + td) * 512 + (lgv * 16 + llv) * 8 + e0]
            = wv;
      }
  }
}

// ---------------------------------------------------------------------------
// Kernel 3: flash attention (unchanged, verified).  Writes X in gemm_out's
// A fragment-image order.
// ---------------------------------------------------------------------------
__global__ __launch_bounds__(256) void attn_k(
    const u16* __restrict__ Q, const u16* __restrict__ Kt, const u16* __restrict__ Vt,
    const float* __restrict__ mbias, u16* __restrict__ Xf)
{
  __shared__ u16 Ls[8192];  // [0,4096): K image tile; [4096,8192): V image tile

  const int tid = threadIdx.x;
  const int w = tid >> 6, l = tid & 63, lg = l >> 4, ll = l & 15;
  const int qb = blockIdx.x, h = blockIdx.y, b = blockIdx.z;
  const size_t qbase = (size_t)(b * 16 + h) * 2048 * 64;
  const size_t tbase = (size_t)((b * 16 + h) * 32) * 4096;
  const int q0 = qb * 64 + w * 16;

  short8 aq[2];
#pragma unroll
  for (int s = 0; s < 2; ++s) {
    V16 v; v.u = *(const u32x4*)&Q[qbase + (size_t)(q0 + ll) * 64 + s * 32 + lg * 8];
    aq[s] = v.s;
  }

  float mrow = -1e30f, lrow = 0.f;
  f32x4 o[4];
#pragma unroll
  for (int td = 0; td < 4; ++td) o[td] = (f32x4){0.f, 0.f, 0.f, 0.f};

  u32x4 rg[4];
#pragma unroll
  for (int q = 0; q < 4; ++q) {
    const int c = w * 4 + q;
    const u16* src = (c < 8) ? Kt : Vt;
    rg[q] = *(const u32x4*)&src[tbase + (c & 7) * 512 + l * 8];
  }

  for (int kt = 0; kt < 32; ++kt) {
    const int j0 = kt * 64;
    __syncthreads();

#pragma unroll
    for (int q = 0; q < 4; ++q) {
      const int c = w * 4 + q;
      *(u32x4*)&Ls[c * 512 + l * 8] = rg[q];
    }
    if (kt + 1 < 32) {
#pragma unroll
      for (int q = 0; q < 4; ++q) {
        const int c = w * 4 + q;
        const u16* src = (c < 8) ? Kt : Vt;
        rg[q] = *(const u32x4*)&src[tbase + (size_t)(kt + 1) * 4096 + (c & 7) * 512 + l * 8];
      }
    }
    __syncthreads();

    f32x4 sc[4];
#pragma unroll
    for (int t = 0; t < 4; ++t) {
      short8 bk0, bk1;
      { V16 v; v.u = *(const u32x4*)&Ls[(t * 2 + 0) * 512 + l * 8]; bk0 = v.s; }
      { V16 v; v.u = *(const u32x4*)&Ls[(t * 2 + 1) * 512 + l * 8]; bk1 = v.s; }
      f32x4 a = (f32x4){0.f, 0.f, 0.f, 0.f};
      a = __builtin_amdgcn_mfma_f32_16x16x32_bf16(bk0, aq[0], a, 0, 0, 0);
      a = __builtin_amdgcn_mfma_f32_16x16x32_bf16(bk1, aq[1], a, 0, 0, 0);
      const f32x4 mb = *(const f32x4*)&mbias[b * 2048 + j0 + ((t >> 1) << 5) + ((t & 1) << 2) + (lg << 3)];
#pragma unroll
      for (int j = 0; j < 4; ++j)
        sc[t][j] = a[j] * 0.125f + mb[j];
    }

    f32x4 mx4;
#pragma unroll
    for (int j = 0; j < 4; ++j)
      mx4[j] = fmaxf(fmaxf(sc[0][j], sc[1][j]), fmaxf(sc[2][j], sc[3][j]));
    float rm = fmaxf(fmaxf(mx4[0], mx4[1]), fmaxf(mx4[2], mx4[3]));
    rm = fmaxf(rm, __shfl_xor(rm, 16));
    rm = fmaxf(rm, __shfl_xor(rm, 32));

    const float mn = fmaxf(mrow, rm);
    const float alpha = __expf(mrow - mn);
    mrow = mn;

    f32x4 p4[4];
    f32x4 s4 = (f32x4){0.f, 0.f, 0.f, 0.f};
#pragma unroll
    for (int t = 0; t < 4; ++t) {
#pragma unroll
      for (int j = 0; j < 4; ++j) {
        p4[t][j] = __expf(sc[t][j] - mn);
        s4[j] += p4[t][j];
      }
    }
    float rs = (s4[0] + s4[1]) + (s4[2] + s4[3]);
    rs += __shfl_xor(rs, 16);
    rs += __shfl_xor(rs, 32);
    lrow = lrow * alpha + rs;
#pragma unroll
    for (int td = 0; td < 4; ++td)
#pragma unroll
      for (int j = 0; j < 4; ++j)
        o[td][j] *= alpha;

#pragma unroll
    for (int s = 0; s < 2; ++s) {
      V16 pb;
      pb.u[0] = cvtpk(p4[2 * s][0], p4[2 * s][1]);
      pb.u[1] = cvtpk(p4[2 * s][2], p4[2 * s][3]);
      pb.u[2] = cvtpk(p4[2 * s + 1][0], p4[2 * s + 1][1]);
      pb.u[3] = cvtpk(p4[2 * s + 1][2], p4[2 * s + 1][3]);
#pragma unroll
      for (int td = 0; td < 4; ++td) {
        V16 v; v.u = *(const u32x4*)&Ls[4096 + (s * 4 + td) * 512 + l * 8];
        o[td] = __builtin_amdgcn_mfma_f32_16x16x32_bf16(v.s, pb.s, o[td], 0, 0, 0);
      }
    }
  }

  const float inv = 1.f / lrow;
  const int m = b * 2048 + q0 + ll;
  const int mt = m >> 7, mr = m & 127;
  const int e0 = (lg & 1) * 4;
#pragma unroll
  for (int td = 0; td < 4; ++td) {
    const int c = ((mr >> 6) << 3) | (((mr >> 4) & 3) << 1) | (td >> 1);
    const int lA = (((td << 1) + (lg >> 1)) & 3) * 16 + (mr & 15);
    u32x2 wv;
    wv[0] = cvtpk(o[td][0] * inv, o[td][1] * inv);
    wv[1] = cvtpk(o[td][2] * inv, o[td][3] * inv);
    *(u32x2*)&Xf[((size_t)(mt * 16 + h) * 16 + c) * 512 + lA * 8 + e0] = wv;
  }
}

// ---------------------------------------------------------------------------
// Kernel 4: output GEMM + bias, same single-buffer reg-prefetch structure.
// ---------------------------------------------------------------------------
__global__ __launch_bounds__(512, 4) void gemm_out_k(
    const u16* __restrict__ Xf, const u16* __restrict__ WoF,
    const float* __restrict__ bo, float* __restrict__ out)
{
  __shared__ u16 As[8192];
  __shared__ u16 Bs[8192];

  const int tid = threadIdx.x;
  const int w = tid >> 6, l = tid & 63, lg = l >> 4, ll = l & 15;
  const int wr = w >> 2, wc = w & 3;
  const int nt = blockIdx.x, mt = blockIdx.y;
  const size_t ab = (size_t)mt * 131072;
  const size_t bb = (size_t)nt * 131072;

  f32x4 acc[4][2];
#pragma unroll
  for (int i = 0; i < 4; ++i)
#pragma unroll
    for (int t = 0; t < 2; ++t)
      acc[i][t] = (f32x4){0.f, 0.f, 0.f, 0.f};

  gld16(Xf + ab + (size_t)w * 512 + l * 8,        &As[w * 512]);
  gld16(Xf + ab + (size_t)(w + 8) * 512 + l * 8,  &As[(w + 8) * 512]);
  gld16(WoF + bb + (size_t)w * 512 + l * 8,       &Bs[w * 512]);
  gld16(WoF + bb + (size_t)(w + 8) * 512 + l * 8, &Bs[(w + 8) * 512]);
  __syncthreads();

  for (int ks = 0; ks < 16; ++ks) {
    short8 afr[2][4], bfr[2][2];
#pragma unroll
    for (int kk = 0; kk < 2; ++kk) {
#pragma unroll
      for (int i = 0; i < 4; ++i) {
        V16 v; v.u = *(const u32x4*)&As[(wr * 8 + i * 2 + kk) * 512 + l * 8];
        afr[kk][i] = v.s;
      }
#pragma unroll
      for (int t = 0; t < 2; ++t) {
        V16 v; v.u = *(const u32x4*)&Bs[((wc >> 1) * 8 + ((wc & 1) * 2 + t) * 2 + kk) * 512 + l * 8];
        bfr[kk][t] = v.s;
      }
    }
    __syncthreads();
    if (ks + 1 < 16) {
      const size_t ao = ab + (size_t)(ks + 1) * 8192;
      const size_t bo2 = bb + (size_t)(ks + 1) * 8192;
      gld16(Xf + ao + (size_t)w * 512 + l * 8,        &As[w * 512]);
      gld16(Xf + ao + (size_t)(w + 8) * 512 + l * 8,  &As[(w + 8) * 512]);
      gld16(WoF + bo2 + (size_t)w * 512 + l * 8,       &Bs[w * 512]);
      gld16(WoF + bo2 + (size_t)(w + 8) * 512 + l * 8, &Bs[(w + 8) * 512]);
    }
#pragma unroll
    for (int kk = 0; kk < 2; ++kk)
#pragma unroll
      for (int i = 0; i < 4; ++i)
#pragma unroll
        for (int t = 0; t < 2; ++t)
          acc[i][t] = __builtin_amdgcn_mfma_f32_16x16x32_bf16(afr[kk][i], bfr[kk][t], acc[i][t], 0, 0, 0);
    __syncthreads();
  }

  const int m0 = mt * 128, n0 = nt * 128;
#pragma unroll
  for (int i = 0; i < 4; ++i)
#pragma unroll
    for (int t = 0; t < 2; ++t) {
      const int n = n0 + wc * 32 + t * 16 + ll;
      const float bv = bo[n];
#pragma unroll
      for (int j = 0; j < 4; ++j) {
        const int m = m0 + wr * 64 + i * 16 + lg * 4 + j;
        out[(size_t)m * 1024 + n] = acc[i][t][j] + bv;
      }
    }
}

// ---------------------------------------------------------------------------
extern "C" void kernel_launch(void* const* d_in, const int* in_sizes, int n_in,
                              void* d_out, int out_size, void* d_ws, size_t ws_size,
                              hipStream_t stream) {
  const float* qry = (const float*)d_in[0];
  const float* key = (const float*)d_in[1];
  const float* val = (const float*)d_in[2];
  const int* mask  = (const int*)d_in[3];
  const float* Wq  = (const float*)d_in[4];
  const float* Wk  = (const float*)d_in[5];
  const float* Wv  = (const float*)d_in[6];
  const float* Wo  = (const float*)d_in[7];
  const float* bo  = (const float*)d_in[8];
  float* out = (float*)d_out;

  char* ws = (char*)d_ws;
  u16* Wt  = (u16*)(ws);                 // [0,6M)   weight B images (q,k,v)
  u16* WoT = (u16*)(ws + 6291456);       // [6M,8M)  Wo B image
  u16* Qw  = (u16*)(ws + 8388608);       // [8M,16M)  Q [b][h][n][64]
  u16* Kw  = (u16*)(ws + 16777216);      // [16M,24M) K attn fragment images
  u16* Vw  = (u16*)(ws + 25165824);      // [24M,32M) V attn fragment images
  u16* Af  = (u16*)(ws + 33554432);      // A images: 24MB (big) or 8MB (small)
  u16* Xw  = (u16*)(ws + 33554432);      // X image (overlaps Af; Af dead by attn)
  float* mbias = (float*)(ws);           // 16 KB, reuses Wt region after gemm_qkv

  wconv<<<dim3(8, 16, 4), 256, 0, stream>>>(Wq, Wk, Wv, Wo, Wt, WoT);

  const bool big = (ws_size >= 58720256ull);
  if (big) {
    aconv<<<dim3(16, 32, 3), 256, 0, stream>>>(qry, key, val, Af, 0, 4194304);
    gemm_qkv_k<<<dim3(8, 32, 3), 512, 0, stream>>>(Af, Wt, Qw, Kw, Vw, 0, 4194304);
  } else {
    for (int z = 0; z < 3; ++z) {
      aconv<<<dim3(16, 32, 1), 256, 0, stream>>>(qry, key, val, Af, z, 0);
      gemm_qkv_k<<<dim3(8, 32, 1), 512, 0, stream>>>(Af, Wt, Qw, Kw, Vw, z, 0);
    }
  }
  mkbias<<<dim3(16, 1, 1), 256, 0, stream>>>(mask, mbias);
  attn_k<<<dim3(32, 16, 2), 256, 0, stream>>>(Qw, Kw, Vw, mbias, Xw);
  gemm_out_k<<<dim3(8, 32, 1), 512, 0, stream>>>(Xw, WoT, bo, out);
}